// Round 1
// baseline (327.732 us; speedup 1.0000x reference)
//
#include <hip/hip_runtime.h>
#include <cstdint>
#include <cstddef>

// ---------------- problem constants ----------------
#define NBD    800                  // B*D slices
#define NPTOT  51200                // total pixels B*D*64
#define SCALEQ 0.17677669529663689f // 32^-0.5

typedef _Float16 half_t;
typedef _Float16 half8   __attribute__((ext_vector_type(8)));
typedef _Float16 half4v  __attribute__((ext_vector_type(4)));
typedef float    float4v __attribute__((ext_vector_type(4)));

#define GLDS16(gp, lp)                                                        \
  __builtin_amdgcn_global_load_lds(                                           \
      (const __attribute__((address_space(1))) void*)(gp),                    \
      (__attribute__((address_space(3))) void*)(lp), 16, 0, 0)

// ---------------- prep kernels ----------------
// dwconv_w (O,C,1,3,3) -> Wt[tap][o][c] fp16
__global__ void prep_convw(const float* __restrict__ w, half_t* __restrict__ Wt) {
  int idx = blockIdx.x * 256 + threadIdx.x;           // < 589824
  int tap = idx >> 16, rem = idx & 65535;
  int o = rem >> 8, c = rem & 255;
  Wt[idx] = (half_t)w[(o * 256 + c) * 9 + tap];
}

// qkv_w fp32 -> fp16, q-rows pre-scaled by SCALE
__global__ void prep_qkvw(const float* __restrict__ w, half_t* __restrict__ W16) {
  int idx = blockIdx.x * 256 + threadIdx.x;           // < 196608
  float v = w[idx];
  if (idx < 65536) v *= SCALEQ;                       // o < 256 => q rows
  W16[idx] = (half_t)v;
}

__global__ void prep_projw(const float* __restrict__ w, half_t* __restrict__ W16) {
  int idx = blockIdx.x * 256 + threadIdx.x;           // < 65536
  W16[idx] = (half_t)w[idx];
}

// btab[head][n][m] = rpb_table[relidx(n,m)][head]
__global__ void prep_bias(const float* __restrict__ rpb, float* __restrict__ btab) {
  int idx = blockIdx.x * 256 + threadIdx.x;           // < 32768
  int hd = idx >> 12, n = (idx >> 6) & 63, m = idx & 63;
  int h1 = n >> 3, w1 = n & 7, h2 = m >> 3, w2 = m & 7;
  int ridx = (h1 - h2 + 7) * 15 + (w1 - w2 + 7);
  btab[idx] = rpb[ridx * 8 + hd];
}

// x (B,C,D,8,8) fp32 -> xpad[bd][10x10 cell][c] fp16, zero-padded borders.
__global__ void prep_xpad(const float* __restrict__ x, half_t* __restrict__ xpad) {
  __shared__ float tile[128 * 65];
  int bd = blockIdx.x, b = bd / 100, d = bd % 100;
  int t = threadIdx.x;
  for (int hf = 0; hf < 2; ++hf) {
    for (int i = 0; i < 32; ++i) {
      int idx = i * 256 + t, c = idx >> 6, hw = idx & 63;
      tile[c * 65 + hw] = x[(size_t)((b * 256 + hf * 128 + c) * 100 + d) * 64 + hw];
    }
    __syncthreads();
    for (int i = 0; i < 50; ++i) {
      int idx = i * 256 + t, cell = idx >> 7, c = idx & 127;
      int hh = cell / 10, ww = cell % 10;
      float v = 0.f;
      if (hh >= 1 && hh <= 8 && ww >= 1 && ww <= 8)
        v = tile[c * 65 + (hh - 1) * 8 + (ww - 1)];
      xpad[(size_t)(bd * 100 + cell) * 256 + hf * 128 + c] = (half_t)v;
    }
    __syncthreads();
  }
}

// ---------------- conv implicit GEMM ----------------
// xl[p][o] = sum_{tap,c} Wt[tap][o][c] * xpad[shift(p,tap)][c] + convb[o]
// 128x128 tile, 4 waves of 64x64 (4x4 16x16x32 mfma), BK=64, 9 taps.
__global__ __launch_bounds__(256) void conv_kernel(
    const half_t* __restrict__ Wt, const half_t* __restrict__ xpad,
    const float* __restrict__ convb, half_t* __restrict__ xl) {
  __shared__ __align__(16) half_t Asm[128 * 64];
  __shared__ __align__(16) half_t Bsm[128 * 64];
  const int blk = blockIdx.x;
  const int o0 = (blk & 1) * 128;
  const int n0 = (blk >> 1) * 128;
  const int tid = threadIdx.x;
  const int wave = tid >> 6, lane = tid & 63;
  const int l15 = lane & 15, quad = lane >> 4;
  const int wm = wave >> 1, wn = wave & 1;
  const int srow = tid >> 3;                 // staging row base (0..31)
  const int cg = (tid & 7) ^ (srow & 7);     // swizzled 16B source chunk

  int pixbase[4], arow[4];
#pragma unroll
  for (int i = 0; i < 4; ++i) {
    int P = n0 + srow + i * 32;
    int bd = P >> 6, hw = P & 63;
    pixbase[i] = (bd * 100 + (hw >> 3) * 10 + (hw & 7)) * 512 + cg * 16;
    arow[i] = (o0 + srow + i * 32) * 512 + cg * 16;
  }

  float4v acc[4][4];
#pragma unroll
  for (int mi = 0; mi < 4; ++mi)
#pragma unroll
    for (int ni = 0; ni < 4; ++ni) {
      float4v z = {0.f, 0.f, 0.f, 0.f};
      acc[mi][ni] = z;
    }

  const char* xpc = (const char*)xpad;
  for (int tap = 0; tap < 9; ++tap) {
    const char* wt = (const char*)Wt + tap * 131072;
    const int toff = ((tap / 3) * 10 + (tap % 3)) * 512;
    for (int c0 = 0; c0 < 512; c0 += 128) {  // bytes, 64 halves per chunk
#pragma unroll
      for (int i = 0; i < 4; ++i) {
        GLDS16(wt + arow[i] + c0, (char*)Asm + i * 4096 + wave * 1024);
        GLDS16(xpc + pixbase[i] + toff + c0, (char*)Bsm + i * 4096 + wave * 1024);
      }
      __syncthreads();
#pragma unroll
      for (int kh = 0; kh < 2; ++kh) {
        half8 af[4], bf[4];
#pragma unroll
        for (int mi = 0; mi < 4; ++mi) {
          int r = wm * 64 + mi * 16 + l15;
          af[mi] = *(const half8*)&Asm[r * 64 + (((kh * 4 + quad) ^ (r & 7)) * 8)];
        }
#pragma unroll
        for (int ni = 0; ni < 4; ++ni) {
          int r = wn * 64 + ni * 16 + l15;
          bf[ni] = *(const half8*)&Bsm[r * 64 + (((kh * 4 + quad) ^ (r & 7)) * 8)];
        }
#pragma unroll
        for (int mi = 0; mi < 4; ++mi)
#pragma unroll
          for (int ni = 0; ni < 4; ++ni)
            acc[mi][ni] = __builtin_amdgcn_mfma_f32_16x16x32_f16(
                af[mi], bf[ni], acc[mi][ni], 0, 0, 0);
      }
      __syncthreads();
    }
  }
  // epilogue: + bias, fp16, store pixel-major xl[p][o]
#pragma unroll
  for (int mi = 0; mi < 4; ++mi) {
    const int o4 = o0 + wm * 64 + mi * 16 + quad * 4;
    const float b0 = convb[o4], b1 = convb[o4 + 1], b2 = convb[o4 + 2], b3 = convb[o4 + 3];
#pragma unroll
    for (int ni = 0; ni < 4; ++ni) {
      const int P = n0 + wn * 64 + ni * 16 + l15;
      half4v h;
      h.x = (half_t)(acc[mi][ni].x + b0);
      h.y = (half_t)(acc[mi][ni].y + b1);
      h.z = (half_t)(acc[mi][ni].z + b2);
      h.w = (half_t)(acc[mi][ni].w + b3);
      *(half4v*)(xl + (size_t)P * 256 + o4) = h;
    }
  }
}

// ---------------- plain GEMM (qkv / proj) ----------------
// MODE 0: qkv (M=768), scatter q/k/v fp16.  MODE 1: proj (M=256), fp32 -> d_out.
template <int MODE, int MT>
__global__ __launch_bounds__(256) void gemm_kernel(
    const half_t* __restrict__ A, const half_t* __restrict__ Bm,
    const float* __restrict__ bias, half_t* __restrict__ qt,
    half_t* __restrict__ kt, half_t* __restrict__ vt, float* __restrict__ out32) {
  __shared__ __align__(16) half_t Asm[128 * 64];
  __shared__ __align__(16) half_t Bsm[128 * 64];
  const int blk = blockIdx.x;
  const int o0 = (blk % MT) * 128;
  const int n0 = (blk / MT) * 128;
  const int tid = threadIdx.x;
  const int wave = tid >> 6, lane = tid & 63;
  const int l15 = lane & 15, quad = lane >> 4;
  const int wm = wave >> 1, wn = wave & 1;
  const int srow = tid >> 3;
  const int cg = (tid & 7) ^ (srow & 7);

  int arow[4], brow[4];
#pragma unroll
  for (int i = 0; i < 4; ++i) {
    arow[i] = (o0 + srow + i * 32) * 512 + cg * 16;
    brow[i] = (n0 + srow + i * 32) * 512 + cg * 16;
  }
  float4v acc[4][4];
#pragma unroll
  for (int mi = 0; mi < 4; ++mi)
#pragma unroll
    for (int ni = 0; ni < 4; ++ni) {
      float4v z = {0.f, 0.f, 0.f, 0.f};
      acc[mi][ni] = z;
    }

  for (int c0 = 0; c0 < 512; c0 += 128) {
#pragma unroll
    for (int i = 0; i < 4; ++i) {
      GLDS16((const char*)A + arow[i] + c0, (char*)Asm + i * 4096 + wave * 1024);
      GLDS16((const char*)Bm + brow[i] + c0, (char*)Bsm + i * 4096 + wave * 1024);
    }
    __syncthreads();
#pragma unroll
    for (int kh = 0; kh < 2; ++kh) {
      half8 af[4], bf[4];
#pragma unroll
      for (int mi = 0; mi < 4; ++mi) {
        int r = wm * 64 + mi * 16 + l15;
        af[mi] = *(const half8*)&Asm[r * 64 + (((kh * 4 + quad) ^ (r & 7)) * 8)];
      }
#pragma unroll
      for (int ni = 0; ni < 4; ++ni) {
        int r = wn * 64 + ni * 16 + l15;
        bf[ni] = *(const half8*)&Bsm[r * 64 + (((kh * 4 + quad) ^ (r & 7)) * 8)];
      }
#pragma unroll
      for (int mi = 0; mi < 4; ++mi)
#pragma unroll
        for (int ni = 0; ni < 4; ++ni)
          acc[mi][ni] = __builtin_amdgcn_mfma_f32_16x16x32_f16(
              af[mi], bf[ni], acc[mi][ni], 0, 0, 0);
    }
    __syncthreads();
  }

  if (MODE == 0) {
    const int part = o0 >> 8;  // 0=q 1=k 2=v, uniform per block
    half_t* base = (part == 0) ? qt : ((part == 1) ? kt : vt);
    const float sc = (part == 0) ? SCALEQ : 1.0f;
#pragma unroll
    for (int mi = 0; mi < 4; ++mi) {
      const int o4 = o0 + wm * 64 + mi * 16 + quad * 4;
      const int oc = o4 & 255, head = oc >> 5, hdc = oc & 31;
      const float b0 = bias[o4] * sc, b1 = bias[o4 + 1] * sc;
      const float b2 = bias[o4 + 2] * sc, b3 = bias[o4 + 3] * sc;
#pragma unroll
      for (int ni = 0; ni < 4; ++ni) {
        const int P = n0 + wn * 64 + ni * 16 + l15;
        const int bd = P >> 6, nn = P & 63;
        const float v0 = acc[mi][ni].x + b0, v1 = acc[mi][ni].y + b1;
        const float v2 = acc[mi][ni].z + b2, v3 = acc[mi][ni].w + b3;
        if (part < 2) {  // q_t/k_t: [bd][head][n][hd]
          half4v h = {(half_t)v0, (half_t)v1, (half_t)v2, (half_t)v3};
          *(half4v*)(base + ((size_t)(bd * 8 + head) * 64 + nn) * 32 + hdc) = h;
        } else {         // v_t: [bd][head][hd][n]
          size_t vb = ((size_t)(bd * 8 + head) * 32 + hdc) * 64 + nn;
          base[vb] = (half_t)v0;
          base[vb + 64] = (half_t)v1;
          base[vb + 128] = (half_t)v2;
          base[vb + 192] = (half_t)v3;
        }
      }
    }
  } else {
#pragma unroll
    for (int mi = 0; mi < 4; ++mi) {
      const int o4 = o0 + wm * 64 + mi * 16 + quad * 4;
      const float b0 = bias[o4], b1 = bias[o4 + 1], b2 = bias[o4 + 2], b3 = bias[o4 + 3];
#pragma unroll
      for (int ni = 0; ni < 4; ++ni) {
        const int P = n0 + wn * 64 + ni * 16 + l15;
        const int b = P / 6400, r = P % 6400, d = r >> 6, nn = r & 63;
        const size_t base0 = (size_t)b * 1638400 + (size_t)d * 64 + nn;
        out32[base0 + (size_t)(o4 + 0) * 6400] = acc[mi][ni].x + b0;
        out32[base0 + (size_t)(o4 + 1) * 6400] = acc[mi][ni].y + b1;
        out32[base0 + (size_t)(o4 + 2) * 6400] = acc[mi][ni].z + b2;
        out32[base0 + (size_t)(o4 + 3) * 6400] = acc[mi][ni].w + b3;
      }
    }
  }
}

// ---------------- attention ----------------
// one wave per (bd, head): S = q^T k (+bias) -> softmax in regs -> P via LDS -> xa^T = v P^T
__global__ __launch_bounds__(256) void attn_kernel(
    const half_t* __restrict__ qt, const half_t* __restrict__ kt,
    const half_t* __restrict__ vt, const float* __restrict__ btab,
    half_t* __restrict__ xa) {
  __shared__ __align__(16) half_t Pl[4][64 * 72];
  const int blk = blockIdx.x;
  const int bd = blk >> 1;
  const int wave = threadIdx.x >> 6, lane = threadIdx.x & 63;
  const int head = (blk & 1) * 4 + wave;
  const int l15 = lane & 15, quad = lane >> 4;
  const half_t* qp = qt + (size_t)(bd * 8 + head) * 2048;
  const half_t* kp = kt + (size_t)(bd * 8 + head) * 2048;
  const half_t* vp = vt + (size_t)(bd * 8 + head) * 2048;

  half8 aq[4], bk[4];
#pragma unroll
  for (int i = 0; i < 4; ++i) {
    aq[i] = *(const half8*)(qp + (i * 16 + l15) * 32 + quad * 8);
    bk[i] = *(const half8*)(kp + (i * 16 + l15) * 32 + quad * 8);
  }
  float4v s[4][4];
#pragma unroll
  for (int ni = 0; ni < 4; ++ni)
#pragma unroll
    for (int mi = 0; mi < 4; ++mi) {
      float4v z = {0.f, 0.f, 0.f, 0.f};
      s[ni][mi] = __builtin_amdgcn_mfma_f32_16x16x32_f16(aq[ni], bk[mi], z, 0, 0, 0);
    }
  // + relative position bias
  const float* bh = btab + head * 4096;
#pragma unroll
  for (int ni = 0; ni < 4; ++ni)
#pragma unroll
    for (int i = 0; i < 4; ++i) {
      const int n = ni * 16 + quad * 4 + i;
#pragma unroll
      for (int mi = 0; mi < 4; ++mi) s[ni][mi][i] += bh[n * 64 + mi * 16 + l15];
    }
  // softmax per row: row n lives in 16 lanes of one quad x 4 mi regs
  float inv[4][4];
#pragma unroll
  for (int ni = 0; ni < 4; ++ni)
#pragma unroll
    for (int i = 0; i < 4; ++i) {
      float mx = fmaxf(fmaxf(s[ni][0][i], s[ni][1][i]), fmaxf(s[ni][2][i], s[ni][3][i]));
      for (int off = 1; off < 16; off <<= 1) mx = fmaxf(mx, __shfl_xor(mx, off));
      float sum = 0.f;
#pragma unroll
      for (int mi = 0; mi < 4; ++mi) {
        float e = __expf(s[ni][mi][i] - mx);
        s[ni][mi][i] = e;
        sum += e;
      }
      for (int off = 1; off < 16; off <<= 1) sum += __shfl_xor(sum, off);
      inv[ni][i] = 1.0f / sum;
    }
  // P -> LDS (n-major, m-contig, stride 72 halves)
#pragma unroll
  for (int ni = 0; ni < 4; ++ni)
#pragma unroll
    for (int i = 0; i < 4; ++i) {
      const int n = ni * 16 + quad * 4 + i;
#pragma unroll
      for (int mi = 0; mi < 4; ++mi)
        Pl[wave][n * 72 + mi * 16 + l15] = (half_t)(s[ni][mi][i] * inv[ni][i]);
    }
  __syncthreads();
  // xa^T(c,n) = v(c,m) . P^T(m,n), K=64
  half8 av[2][2];
#pragma unroll
  for (int ci = 0; ci < 2; ++ci)
#pragma unroll
    for (int k2 = 0; k2 < 2; ++k2)
      av[ci][k2] = *(const half8*)(vp + (ci * 16 + l15) * 64 + k2 * 32 + quad * 8);
  float4v oa[2][4];
#pragma unroll
  for (int ci = 0; ci < 2; ++ci)
#pragma unroll
    for (int ni = 0; ni < 4; ++ni) {
      float4v z = {0.f, 0.f, 0.f, 0.f};
      oa[ci][ni] = z;
    }
#pragma unroll
  for (int ni = 0; ni < 4; ++ni)
#pragma unroll
    for (int k2 = 0; k2 < 2; ++k2) {
      half8 bp = *(const half8*)&Pl[wave][(ni * 16 + l15) * 72 + k2 * 32 + quad * 8];
#pragma unroll
      for (int ci = 0; ci < 2; ++ci)
        oa[ci][ni] = __builtin_amdgcn_mfma_f32_16x16x32_f16(av[ci][k2], bp, oa[ci][ni], 0, 0, 0);
    }
  // store xa[p][c] fp16
#pragma unroll
  for (int ci = 0; ci < 2; ++ci)
#pragma unroll
    for (int ni = 0; ni < 4; ++ni) {
      half4v h = {(half_t)oa[ci][ni].x, (half_t)oa[ci][ni].y,
                  (half_t)oa[ci][ni].z, (half_t)oa[ci][ni].w};
      *(half4v*)(xa + (size_t)(bd * 64 + ni * 16 + l15) * 256 + head * 32 + ci * 16 + quad * 4) = h;
    }
}

// ---------------- launch ----------------
extern "C" void kernel_launch(void* const* d_in, const int* in_sizes, int n_in,
                              void* d_out, int out_size, void* d_ws, size_t ws_size,
                              hipStream_t stream) {
  const float* x        = (const float*)d_in[0];
  const float* dwconv_w = (const float*)d_in[1];
  const float* dwconv_b = (const float*)d_in[2];
  const float* qkv_w    = (const float*)d_in[3];
  const float* qkv_b    = (const float*)d_in[4];
  const float* proj_w   = (const float*)d_in[5];
  const float* proj_b   = (const float*)d_in[6];
  const float* rpb      = (const float*)d_in[7];
  float* out = (float*)d_out;

  char* ws = (char*)d_ws;
  size_t off = 0;
  half_t* xpad = (half_t*)(ws + off); off += 40960000;   // 800*100*256 fp16
  half_t* xl   = (half_t*)(ws + off); off += 26214400;   // 51200*256 fp16
  half_t* qt   = (half_t*)(ws + off); off += 26214400;   // [bd][h][n][hd]
  half_t* kt   = (half_t*)(ws + off); off += 26214400;
  half_t* vt   = (half_t*)(ws + off); off += 26214400;   // [bd][h][hd][n]
  half_t* xa   = (half_t*)(ws + off); off += 26214400;   // [p][c]
  half_t* Wt   = (half_t*)(ws + off); off += 1179648;    // [9][256][256]
  half_t* qw16 = (half_t*)(ws + off); off += 393216;
  half_t* pw16 = (half_t*)(ws + off); off += 131072;
  float*  btab = (float*)(ws + off);  off += 131072;     // [8][64][64]

  prep_convw<<<2304, 256, 0, stream>>>(dwconv_w, Wt);
  prep_qkvw<<<768, 256, 0, stream>>>(qkv_w, qw16);
  prep_projw<<<256, 256, 0, stream>>>(proj_w, pw16);
  prep_bias<<<128, 256, 0, stream>>>(rpb, btab);
  prep_xpad<<<800, 256, 0, stream>>>(x, xpad);

  conv_kernel<<<800, 256, 0, stream>>>(Wt, xpad, dwconv_b, xl);
  gemm_kernel<0, 6><<<2400, 256, 0, stream>>>(qw16, xl, qkv_b, qt, kt, vt, nullptr);
  attn_kernel<<<1600, 256, 0, stream>>>(qt, kt, vt, btab, xa);
  gemm_kernel<1, 2><<<800, 256, 0, stream>>>(pw16, xa, proj_b, nullptr, nullptr, nullptr, out);
}